// Round 20
// baseline (72.739 us; speedup 1.0000x reference)
//
#include <hip/hip_runtime.h>
#include <hip/hip_bf16.h>

#define TT 2048
#define DDIM 1024
#define NHEAD 16
#define HD 64
#define QBLK 64
#define KVBLK 64
#define NQT (TT / QBLK)

typedef float f32x4 __attribute__((ext_vector_type(4)));
typedef short bf16x8 __attribute__((ext_vector_type(8)));

__device__ __forceinline__ ushort f2bf(float f) {
    __hip_bfloat16 h = __float2bfloat16(f);
    return *reinterpret_cast<ushort*>(&h);
}

// Counted-wait barrier, HARDENED (R17 lesson): sched_barrier(0) both sides
// (s_barrier has no motion semantics in LLVM); lgkmcnt(0) drains this wave's
// LDS writes; prefetch global loads stay in flight (R11's +22us lever).
__device__ __forceinline__ void barrier_lgkm_only() {
    __builtin_amdgcn_sched_barrier(0);
    asm volatile("s_waitcnt lgkmcnt(0)" ::: "memory");
    __builtin_amdgcn_s_barrier();
    __builtin_amdgcn_sched_barrier(0);
}

// ============ pre-pass (R8-proven): K -> bf16, V -> bf16 transposed ============
__global__ __launch_bounds__(256)
void prepass_kernel(const float* __restrict__ kg, const float* __restrict__ vg,
                    ushort* __restrict__ kbf, ushort* __restrict__ vt) {
    __shared__ float vtile[64][65];
    const int tid = threadIdx.x;
    const int kv0 = (int)blockIdx.x * 64;
    const int bh  = (int)blockIdx.y;
    const int b = bh >> 4, h = bh & 15;
    const int row = tid >> 2;
    const int c0  = (tid & 3) * 16;
    const size_t gin = ((size_t)(b * TT + kv0 + row)) * DDIM + h * HD + c0;
    {
        ushort o[16];
        #pragma unroll
        for (int i = 0; i < 4; ++i) {
            float4 a = *(const float4*)(kg + gin + i * 4);
            o[i*4+0]=f2bf(a.x); o[i*4+1]=f2bf(a.y); o[i*4+2]=f2bf(a.z); o[i*4+3]=f2bf(a.w);
        }
        ushort* kout = kbf + ((size_t)bh * TT + kv0 + row) * HD + c0;
        *(bf16x8*)kout       = *(bf16x8*)&o[0];
        *(bf16x8*)(kout + 8) = *(bf16x8*)&o[8];
    }
    #pragma unroll
    for (int i = 0; i < 4; ++i) {
        float4 a = *(const float4*)(vg + gin + i * 4);
        vtile[row][c0 + i*4 + 0] = a.x;
        vtile[row][c0 + i*4 + 1] = a.y;
        vtile[row][c0 + i*4 + 2] = a.z;
        vtile[row][c0 + i*4 + 3] = a.w;
    }
    __syncthreads();
    {
        ushort o[16];
        #pragma unroll
        for (int i = 0; i < 16; ++i) o[i] = f2bf(vtile[c0 + i][row]);
        ushort* vout = vt + ((size_t)bh * HD + row) * TT + kv0 + c0;
        *(bf16x8*)vout       = *(bf16x8*)&o[0];
        *(bf16x8*)(vout + 8) = *(bf16x8*)&o[8];
    }
}

// ============ main: R19 pipeline + peeled diagonal + folded-bias softmax ============
// Hot loop is mask-free; bz[i] = relb2 + c2[i] - m kept in 16 regs (static
// indices), advanced by -64*slope2 per iter; p = exp2(fmaf(sa, sc2, bz)).
// Defer-max check: __all(tm <= 8). P aliased into idle lds_v[buf^1] (R16).
__global__ __launch_bounds__(256, 2)
void attn_main(const float* __restrict__ qg, const ushort* __restrict__ kbf,
               const ushort* __restrict__ vt, float* __restrict__ out) {
    __shared__ __align__(16) ushort lds_k[2][KVBLK * HD];
    __shared__ __align__(16) ushort lds_v[2][HD * KVBLK];

    const int tid  = threadIdx.x;
    const int wv   = tid >> 6;
    const int lane = tid & 63;
    const int hi   = lane >> 4;
    const int qr   = lane & 15;

    // XCD decode (R6-proven) + balanced qt map (R7/R11)
    const int flat = (int)blockIdx.x;          // 0..1023
    const int xcd  = flat & 7;
    const int idx  = flat >> 3;
    const int bs   = idx >> 5;
    const int s    = idx & 31;
    const int bh   = xcd * 4 + bs;
    const int qt   = (bs & 1) ? s : (NQT - 1 - s);
    const int b    = bh >> 4;
    const int h    = bh & 15;
    const int q0   = qt * QBLK;

    const float LOG2E  = 1.4426950408889634f;
    const float slope2 = exp2f(-0.5f * (float)(h + 1)) * LOG2E;
    const float sc2    = 0.125f * LOG2E;
    float c2[16];
    #pragma unroll
    for (int st = 0; st < 4; ++st)
        #pragma unroll
        for (int rr = 0; rr < 4; ++rr) c2[st * 4 + rr] = (float)(st * 16 + rr) * slope2;

    // ---- Q fragments ----
    bf16x8 qf[2];
    {
        const float* gq = qg + ((size_t)(b * TT + q0 + wv * 16 + qr)) * DDIM + h * HD + hi * 8;
        #pragma unroll
        for (int ch = 0; ch < 2; ++ch) {
            float4 a0 = *(const float4*)(gq + ch * 32);
            float4 a1 = *(const float4*)(gq + ch * 32 + 4);
            bf16x8 w;
            w[0]=f2bf(a0.x); w[1]=f2bf(a0.y); w[2]=f2bf(a0.z); w[3]=f2bf(a0.w);
            w[4]=f2bf(a1.x); w[5]=f2bf(a1.y); w[6]=f2bf(a1.z); w[7]=f2bf(a1.w);
            qf[ch] = w;
        }
    }

    const ushort* kb = kbf + (size_t)bh * TT * HD;
    const ushort* vb = vt  + (size_t)bh * HD * TT;

    const int srow = tid >> 2;
    const int sci  = tid & 3;
    const int sw   = srow & 7;

    bf16x8 kr0, kr1, vr0, vr1;
    const ushort* kp = kb + (size_t)(q0 + srow) * HD + sci * 8;
    const ushort* vp = vb + (size_t)srow * TT + q0 + sci * 8;
    auto stage_issue = [&]() {
        kr0 = *(const bf16x8*)kp;  kr1 = *(const bf16x8*)(kp + 32);
        vr0 = *(const bf16x8*)vp;  vr1 = *(const bf16x8*)(vp + 32);
        kp -= (size_t)KVBLK * HD;  vp -= KVBLK;
    };
    auto stage_write = [&](int nb) {
        *(bf16x8*)&lds_k[nb][srow * 64 + ((sci ^ sw) << 3)]       = kr0;
        *(bf16x8*)&lds_k[nb][srow * 64 + (((sci + 4) ^ sw) << 3)] = kr1;
        *(bf16x8*)&lds_v[nb][srow * 64 + ((sci ^ sw) << 3)]       = vr0;
        *(bf16x8*)&lds_v[nb][srow * 64 + (((sci + 4) ^ sw) << 3)] = vr1;
    };

    const int nit = qt + 1;
    stage_issue();
    stage_write(0);

    f32x4 oacc[4] = {};
    float lrun = 0.f;
    const int ti = q0 + wv * 16 + qr;
    float bz[16];           // bias-minus-max registers (static indexing only)
    const float vstep = 64.f * slope2;

    // ================= peeled diagonal iteration (j=0, buf=0) =================
    {
        if (nit > 1) stage_issue();
        barrier_lgkm_only();
        ushort* pb = &lds_v[1][wv * 1024];

        f32x4 sa[4] = {};
        __builtin_amdgcn_s_setprio(1);
        #pragma unroll
        for (int st = 0; st < 4; ++st) {
            if (st <= wv) {
                const int krow = st * 16 + qr;
                const int ksw = (krow & 7);
                bf16x8 k0 = *(const bf16x8*)&lds_k[0][krow * 64 + ((hi ^ ksw) << 3)];
                bf16x8 k1 = *(const bf16x8*)&lds_k[0][krow * 64 + (((4 + hi) ^ ksw) << 3)];
                sa[st] = __builtin_amdgcn_mfma_f32_16x16x32_bf16(k0, qf[0], sa[st], 0, 0, 0);
                sa[st] = __builtin_amdgcn_mfma_f32_16x16x32_bf16(k1, qf[1], sa[st], 0, 0, 0);
            }
        }
        __builtin_amdgcn_s_setprio(0);

        const float relb = (float)(q0 - ti + hi * 4);
        float xv[16];
        float tm = -INFINITY;
        #pragma unroll
        for (int st = 0; st < 4; ++st)
            #pragma unroll
            for (int rr = 0; rr < 4; ++rr) {
                const float rel = relb + (float)(st * 16 + rr);   // exact small ints
                float v = fmaf(sa[st][rr], sc2, rel * slope2);
                v = (rel <= 0.f && st <= wv) ? v : -INFINITY;
                xv[st * 4 + rr] = v;
                tm = fmaxf(tm, v);
            }
        tm = fmaxf(tm, __shfl_xor(tm, 16));
        tm = fmaxf(tm, __shfl_xor(tm, 32));
        const float m0 = tm;   // finite: diagonal element always valid
        float psum = 0.f;
        #pragma unroll
        for (int i = 0; i < 16; ++i) { xv[i] = exp2f(xv[i] - m0); psum += xv[i]; }
        lrun = psum;

        #pragma unroll
        for (int st = 0; st < 4; ++st) {
            ushort4 w;
            w.x = f2bf(xv[st * 4 + 0]); w.y = f2bf(xv[st * 4 + 1]);
            w.z = f2bf(xv[st * 4 + 2]); w.w = f2bf(xv[st * 4 + 3]);
            const int slot8 = (st << 1) | (hi >> 1);
            *(ushort4*)&pb[qr * 64 + ((slot8 ^ (qr & 7)) << 3) + ((hi & 1) << 2)] = w;
        }

        __builtin_amdgcn_s_setprio(1);
        #pragma unroll
        for (int ks = 0; ks < 2; ++ks) {
            if (wv >= 2 || ks == 0) {
                bf16x8 pa = *(const bf16x8*)&pb[qr * 64 + ((((ks << 2) | hi) ^ (qr & 7)) << 3)];
                #pragma unroll
                for (int dt = 0; dt < 4; ++dt) {
                    const int dv = dt * 16 + qr;
                    bf16x8 vbf = *(const bf16x8*)&lds_v[0][dv * 64 + ((((ks << 2) + hi) ^ (dv & 7)) << 3)];
                    oacc[dt] = __builtin_amdgcn_mfma_f32_16x16x32_bf16(pa, vbf, oacc[dt], 0, 0, 0);
                }
            }
        }
        __builtin_amdgcn_s_setprio(0);

        if (nit > 1) stage_write(1);

        // init bias-minus-max registers for j=1
        const float relb1 = (float)(q0 - KVBLK - ti + hi * 4) * slope2;
        #pragma unroll
        for (int i = 0; i < 16; ++i) bz[i] = relb1 + c2[i] - m0;
    }

    // ======================= mask-free hot loop (j>=1) =======================
    for (int j = 1; j < nit; ++j) {
        const int buf = j & 1;
        if (j + 1 < nit) stage_issue();   // loads stay in flight ACROSS the barrier
        barrier_lgkm_only();

        ushort* pb = &lds_v[buf ^ 1][wv * 1024];

        // ---- S^T = K Q^T (all 4 sub-tiles) ----
        f32x4 sa[4] = {};
        __builtin_amdgcn_s_setprio(1);
        #pragma unroll
        for (int st = 0; st < 4; ++st) {
            const int krow = st * 16 + qr;
            const int ksw = (krow & 7);
            bf16x8 k0 = *(const bf16x8*)&lds_k[buf][krow * 64 + ((hi ^ ksw) << 3)];
            bf16x8 k1 = *(const bf16x8*)&lds_k[buf][krow * 64 + (((4 + hi) ^ ksw) << 3)];
            sa[st] = __builtin_amdgcn_mfma_f32_16x16x32_bf16(k0, qf[0], sa[st], 0, 0, 0);
            sa[st] = __builtin_amdgcn_mfma_f32_16x16x32_bf16(k1, qf[1], sa[st], 0, 0, 0);
        }
        __builtin_amdgcn_s_setprio(0);

        // ---- lean softmax: v = x - m directly; tree-max; no masks ----
        float v[16];
        #pragma unroll
        for (int st = 0; st < 4; ++st)
            #pragma unroll
            for (int rr = 0; rr < 4; ++rr)
                v[st * 4 + rr] = fmaf(sa[st][rr], sc2, bz[st * 4 + rr]);
        float m01 = fmaxf(v[0], v[1]),   m23 = fmaxf(v[2], v[3]);
        float m45 = fmaxf(v[4], v[5]),   m67 = fmaxf(v[6], v[7]);
        float m89 = fmaxf(v[8], v[9]),   mAB = fmaxf(v[10], v[11]);
        float mCD = fmaxf(v[12], v[13]), mEF = fmaxf(v[14], v[15]);
        float q03 = fmaxf(m01, m23), q47 = fmaxf(m45, m67);
        float q8B = fmaxf(m89, mAB), qCF = fmaxf(mCD, mEF);
        float tm  = fmaxf(fmaxf(q03, q47), fmaxf(q8B, qCF));
        if (!__all(tm <= 8.f)) {          // rare rescale
            float tmr = fmaxf(tm, __shfl_xor(tm, 16));
            tmr = fmaxf(tmr, __shfl_xor(tmr, 32));
            const float d   = fmaxf(tmr, 0.f);
            const float fsc = exp2f(-d);
            #pragma unroll
            for (int i = 0; i < 16; ++i) { bz[i] -= d; v[i] -= d; }
            lrun *= fsc;
            float fo[4];
            #pragma unroll
            for (int rr = 0; rr < 4; ++rr) fo[rr] = __shfl(fsc, hi * 4 + rr);
            #pragma unroll
            for (int dt = 0; dt < 4; ++dt)
                #pragma unroll
                for (int rr = 0; rr < 4; ++rr) oacc[dt][rr] *= fo[rr];
        }
        float psum = 0.f;
        #pragma unroll
        for (int i = 0; i < 16; ++i) { v[i] = exp2f(v[i]); psum += v[i]; }
        lrun += psum;

        // ---- P -> aliased LDS slot ----
        #pragma unroll
        for (int st = 0; st < 4; ++st) {
            ushort4 w;
            w.x = f2bf(v[st * 4 + 0]); w.y = f2bf(v[st * 4 + 1]);
            w.z = f2bf(v[st * 4 + 2]); w.w = f2bf(v[st * 4 + 3]);
            const int slot8 = (st << 1) | (hi >> 1);
            *(ushort4*)&pb[qr * 64 + ((slot8 ^ (qr & 7)) << 3) + ((hi & 1) << 2)] = w;
        }

        // ---- O += P V (both halves, no guards) ----
        __builtin_amdgcn_s_setprio(1);
        #pragma unroll
        for (int ks = 0; ks < 2; ++ks) {
            bf16x8 pa = *(const bf16x8*)&pb[qr * 64 + ((((ks << 2) | hi) ^ (qr & 7)) << 3)];
            #pragma unroll
            for (int dt = 0; dt < 4; ++dt) {
                const int dv = dt * 16 + qr;
                bf16x8 vbf = *(const bf16x8*)&lds_v[buf][dv * 64 + ((((ks << 2) + hi) ^ (dv & 7)) << 3)];
                oacc[dt] = __builtin_amdgcn_mfma_f32_16x16x32_bf16(pa, vbf, oacc[dt], 0, 0, 0);
            }
        }
        __builtin_amdgcn_s_setprio(0);

        // advance bias for next iteration (descending kv)
        #pragma unroll
        for (int i = 0; i < 16; ++i) bz[i] -= vstep;

        if (j + 1 < nit) stage_write(buf ^ 1);   // vmcnt wait lands here
    }

    // ---- epilogue ----
    {
        float lr = lrun;
        lr += __shfl_xor(lr, 16);
        lr += __shfl_xor(lr, 32);
        const float linv = 1.0f / lr;
        #pragma unroll
        for (int rr = 0; rr < 4; ++rr) {
            const float inv = __shfl(linv, hi * 4 + rr);
            float* go = out + ((size_t)(b * TT + q0 + wv * 16 + hi * 4 + rr)) * DDIM + h * HD;
            #pragma unroll
            for (int dt = 0; dt < 4; ++dt)
                go[dt * 16 + qr] = oacc[dt][rr] * inv;
        }
    }
}

// ============ fallback (R6 kernel, proven 76.5us) if ws too small ============
#define VST 72
__global__ __launch_bounds__(256, 2)
void alibi_attn_fallback(const float* __restrict__ qg,
                         const float* __restrict__ kg,
                         const float* __restrict__ vg,
                         float* __restrict__ out) {
    __shared__ __align__(16) ushort lds_k[KVBLK * HD];
    __shared__ __align__(16) ushort lds_vt[HD * VST];
    __shared__ __align__(16) ushort lds_p[4][16 * 64];

    const int tid  = threadIdx.x;
    const int wv   = tid >> 6;
    const int lane = tid & 63;
    const int hi   = lane >> 4;
    const int qr   = lane & 15;

    const int flat = (int)blockIdx.x;
    const int xcd  = flat & 7;
    const int idx  = flat >> 3;
    const int bh   = xcd * 4 + (idx >> 5);
    const int qt   = NQT - 1 - (idx & 31);
    const int b    = bh >> 4;
    const int h    = bh & 15;
    const int q0   = qt * QBLK;

    const float LOG2E  = 1.4426950408889634f;
    const float slope2 = exp2f(-0.5f * (float)(h + 1)) * LOG2E;
    const float sc2    = 0.125f * LOG2E;

    const size_t bhbase = (size_t)(b * TT) * DDIM + (size_t)(h * HD);

    bf16x8 qf[2];
    {
        const float* gq = qg + bhbase + (size_t)(q0 + wv * 16 + qr) * DDIM + hi * 8;
        #pragma unroll
        for (int ch = 0; ch < 2; ++ch) {
            float4 a0 = *(const float4*)(gq + ch * 32);
            float4 a1 = *(const float4*)(gq + ch * 32 + 4);
            bf16x8 w;
            w[0]=f2bf(a0.x); w[1]=f2bf(a0.y); w[2]=f2bf(a0.z); w[3]=f2bf(a0.w);
            w[4]=f2bf(a1.x); w[5]=f2bf(a1.y); w[6]=f2bf(a1.z); w[7]=f2bf(a1.w);
            qf[ch] = w;
        }
    }

    const int krow = tid >> 3;
    const int kcg  = tid & 7;
    const int vdv  = tid & 63;
    const int vkc  = tid >> 6;

    float ka[2][8], va[2][8];
    auto issue_loads = [&](int kv0) {
        const float* kp0 = kg + bhbase + (size_t)(kv0 + krow) * DDIM + kcg * 8;
        const float* kp1 = kp0 + (size_t)32 * DDIM;
        *(float4*)&ka[0][0] = *(const float4*)kp0; *(float4*)&ka[0][4] = *(const float4*)(kp0 + 4);
        *(float4*)&ka[1][0] = *(const float4*)kp1; *(float4*)&ka[1][4] = *(const float4*)(kp1 + 4);
        const float* vp0 = vg + bhbase + (size_t)(kv0 + vkc * 8) * DDIM + vdv;
        const float* vp1 = vp0 + (size_t)32 * DDIM;
        #pragma unroll
        for (int jj = 0; jj < 8; ++jj) {
            va[0][jj] = vp0[(size_t)jj * DDIM];
            va[1][jj] = vp1[(size_t)jj * DDIM];
        }
    };
    auto write_stage = [&]() {
        #pragma unroll
        for (int s2 = 0; s2 < 2; ++s2) {
            bf16x8 w;
            #pragma unroll
            for (int e = 0; e < 8; ++e) w[e] = f2bf(ka[s2][e]);
            const int row = krow + s2 * 32;
            *(bf16x8*)&lds_k[row * 64 + ((kcg ^ (row & 7)) << 3)] = w;
            bf16x8 u;
            #pragma unroll
            for (int e = 0; e < 8; ++e) u[e] = f2bf(va[s2][e]);
            const int kc = vkc + s2 * 4;
            *(bf16x8*)&lds_vt[vdv * VST + ((kc ^ ((vdv >> 3) & 7)) << 3)] = u;
        }
    };

    const int nit = qt + 1;
    issue_loads(q0);
    write_stage();

    f32x4 oacc[4] = {};
    float mrun = -INFINITY, lrun = 0.f;

    for (int j = 0; j < nit; ++j) {
        const int kv0 = (qt - j) * KVBLK;
        if (j + 1 < nit) issue_loads(kv0 - KVBLK);
        __syncthreads();

        const bool diag = (j == 0);

        f32x4 s_acc[4] = {};
        __builtin_amdgcn_s_setprio(1);
        #pragma unroll
        for (int st = 0; st < 4; ++st) {
            if (!diag || st <= wv) {
                const int kvrow = st * 16 + qr;
                #pragma unroll
                for (int ch = 0; ch < 2; ++ch) {
                    bf16x8 kf = *(const bf16x8*)&lds_k[kvrow * 64 + ((((ch << 2) + hi) ^ (kvrow & 7)) << 3)];
                    s_acc[st] = __builtin_amdgcn_mfma_f32_16x16x32_bf16(kf, qf[ch], s_acc[st], 0, 0, 0);
                }
            }
        }
        __builtin_amdgcn_s_setprio(0);

        const int ti = q0 + wv * 16 + qr;
        float xv[16];
        float tm = -INFINITY;
        {
            const float relb = (float)(kv0 - ti);
            #pragma unroll
            for (int st = 0; st < 4; ++st)
                #pragma unroll
                for (int rr = 0; rr < 4; ++rr) {
                    const float rel = relb + (float)(st * 16 + hi * 4 + rr);
                    float v = s_acc[st][rr] * sc2 + rel * slope2;
                    if (diag) v = (rel <= 0.f) ? v : -INFINITY;
                    xv[st * 4 + rr] = v;
                    tm = fmaxf(tm, v);
                }
        }
        tm = fmaxf(tm, __shfl_xor(tm, 16));
        tm = fmaxf(tm, __shfl_xor(tm, 32));
        if (!__all(tm <= mrun + 8.f)) {
            const float mnew = fmaxf(mrun, tm);
            const float fsc  = exp2f(mrun - mnew);
            mrun = mnew;
            lrun *= fsc;
            float fo[4];
            #pragma unroll
            for (int rr = 0; rr < 4; ++rr) fo[rr] = __shfl(fsc, hi * 4 + rr);
            #pragma unroll
            for (int dt = 0; dt < 4; ++dt)
                #pragma unroll
                for (int rr = 0; rr < 4; ++rr) oacc[dt][rr] *= fo[rr];
        }
        float psum = 0.f;
        #pragma unroll
        for (int i = 0; i < 16; ++i) { xv[i] = exp2f(xv[i] - mrun); psum += xv[i]; }
        lrun += psum;

        #pragma unroll
        for (int st = 0; st < 4; ++st) {
            ushort4 w;
            w.x = f2bf(xv[st * 4 + 0]); w.y = f2bf(xv[st * 4 + 1]);
            w.z = f2bf(xv[st * 4 + 2]); w.w = f2bf(xv[st * 4 + 3]);
            const int slot8 = (st << 1) | (hi >> 1);
            *(ushort4*)&lds_p[wv][qr * 64 + ((slot8 ^ (qr & 7)) << 3) + ((hi & 1) << 2)] = w;
        }

        __builtin_amdgcn_s_setprio(1);
        #pragma unroll
        for (int ks = 0; ks < 2; ++ks) {
            if (!diag || wv >= 2 || ks == 0) {
                bf16x8 pa = *(const bf16x8*)&lds_p[wv][qr * 64 + ((((ks << 2) | hi) ^ (qr & 7)) << 3)];
                #pragma unroll
                for (int dt = 0; dt < 4; ++dt) {
                    const int dv = dt * 16 + qr;
                    bf16x8 vbf = *(const bf16x8*)&lds_vt[dv * VST + ((((ks << 2) + hi) ^ ((dv >> 3) & 7)) << 3)];
                    oacc[dt] = __builtin_amdgcn_mfma_f32_16x16x32_bf16(pa, vbf, oacc[dt], 0, 0, 0);
                }
            }
        }
        __builtin_amdgcn_s_setprio(0);

        if (j + 1 < nit) {
            __syncthreads();
            write_stage();
        }
    }

    {
        float lr = lrun;
        lr += __shfl_xor(lr, 16);
        lr += __shfl_xor(lr, 32);
        const float linv = 1.0f / lr;
        #pragma unroll
        for (int rr = 0; rr < 4; ++rr) {
            const float inv = __shfl(linv, hi * 4 + rr);
            float* go = out + bhbase + (size_t)(q0 + wv * 16 + hi * 4 + rr) * DDIM;
            #pragma unroll
            for (int dt = 0; dt < 4; ++dt)
                go[dt * 16 + qr] = oacc[dt][rr] * inv;
        }
    }
}

extern "C" void kernel_launch(void* const* d_in, const int* in_sizes, int n_in,
                              void* d_out, int out_size, void* d_ws, size_t ws_size,
                              hipStream_t stream) {
    (void)in_sizes; (void)n_in; (void)out_size;
    const float* q = (const float*)d_in[0];
    const float* k = (const float*)d_in[1];
    const float* v = (const float*)d_in[2];
    float* o = (float*)d_out;

    const size_t elems = (size_t)2 * NHEAD * TT * HD;
    const size_t kv_b  = 2 * elems * sizeof(ushort);       // 16.78 MB
    if (ws_size >= kv_b) {
        ushort* kbf = (ushort*)d_ws;
        ushort* vtt = kbf + elems;
        prepass_kernel<<<dim3(32, 32), 256, 0, stream>>>(k, v, kbf, vtt);
        attn_main<<<dim3(1024), 256, 0, stream>>>(q, kbf, vtt, o);
    } else {
        alibi_attn_fallback<<<dim3(1024), 256, 0, stream>>>(q, k, v, o);
    }
}

// Round 21
// 61.701 us; speedup vs baseline: 1.1789x; 1.1789x over previous
//
#include <hip/hip_runtime.h>
#include <hip/hip_bf16.h>

#define TT 2048
#define DDIM 1024
#define NHEAD 16
#define HD 64
#define QBLK 64
#define KVBLK 64
#define NQT (TT / QBLK)

typedef float f32x4 __attribute__((ext_vector_type(4)));
typedef short bf16x8 __attribute__((ext_vector_type(8)));

__device__ __forceinline__ ushort f2bf(float f) {
    __hip_bfloat16 h = __float2bfloat16(f);
    return *reinterpret_cast<ushort*>(&h);
}

// Counted-wait barrier, HARDENED (R17 lesson): s_barrier has NO memory/motion
// semantics in LLVM — sched_barrier(0) on both sides stops ds_reads hoisting
// above it (cross-wave race). lgkmcnt(0) drains this wave's LDS writes;
// prefetch global loads stay in flight (no vmcnt drain — R11's +22us lever).
__device__ __forceinline__ void barrier_lgkm_only() {
    __builtin_amdgcn_sched_barrier(0);
    asm volatile("s_waitcnt lgkmcnt(0)" ::: "memory");
    __builtin_amdgcn_s_barrier();
    __builtin_amdgcn_sched_barrier(0);
}

// ============ pre-pass (R8-proven): K -> bf16, V -> bf16 transposed ============
__global__ __launch_bounds__(256)
void prepass_kernel(const float* __restrict__ kg, const float* __restrict__ vg,
                    ushort* __restrict__ kbf, ushort* __restrict__ vt) {
    __shared__ float vtile[64][65];
    const int tid = threadIdx.x;
    const int kv0 = (int)blockIdx.x * 64;
    const int bh  = (int)blockIdx.y;
    const int b = bh >> 4, h = bh & 15;
    const int row = tid >> 2;
    const int c0  = (tid & 3) * 16;
    const size_t gin = ((size_t)(b * TT + kv0 + row)) * DDIM + h * HD + c0;
    {
        ushort o[16];
        #pragma unroll
        for (int i = 0; i < 4; ++i) {
            float4 a = *(const float4*)(kg + gin + i * 4);
            o[i*4+0]=f2bf(a.x); o[i*4+1]=f2bf(a.y); o[i*4+2]=f2bf(a.z); o[i*4+3]=f2bf(a.w);
        }
        ushort* kout = kbf + ((size_t)bh * TT + kv0 + row) * HD + c0;
        *(bf16x8*)kout       = *(bf16x8*)&o[0];
        *(bf16x8*)(kout + 8) = *(bf16x8*)&o[8];
    }
    #pragma unroll
    for (int i = 0; i < 4; ++i) {
        float4 a = *(const float4*)(vg + gin + i * 4);
        vtile[row][c0 + i*4 + 0] = a.x;
        vtile[row][c0 + i*4 + 1] = a.y;
        vtile[row][c0 + i*4 + 2] = a.z;
        vtile[row][c0 + i*4 + 3] = a.w;
    }
    __syncthreads();
    {
        ushort o[16];
        #pragma unroll
        for (int i = 0; i < 16; ++i) o[i] = f2bf(vtile[c0 + i][row]);
        ushort* vout = vt + ((size_t)bh * HD + row) * TT + kv0 + c0;
        *(bf16x8*)vout       = *(bf16x8*)&o[0];
        *(bf16x8*)(vout + 8) = *(bf16x8*)&o[8];
    }
}

// ============ main: R11 pipeline + 32KB P-alias + hardened barrier ============
// (R19-proven 61.9us total — session best. R20's peel+folded-bias softmax
//  regressed to 72.7us: -12% VALU but occupancy 28->19 from code-size/live-range
//  growth. Reverted.)
// P slot of wave w == wave w's own V-staging region in lds_v[buf^1] (idle from
// barrier until stage_write; same-wave LDS ops are in-order). 32KB -> 5/CU
// LDS-cap; grid 1024 = 4/CU.
__global__ __launch_bounds__(256, 2)
void attn_main(const float* __restrict__ qg, const ushort* __restrict__ kbf,
               const ushort* __restrict__ vt, float* __restrict__ out) {
    __shared__ __align__(16) ushort lds_k[2][KVBLK * HD];
    __shared__ __align__(16) ushort lds_v[2][HD * KVBLK];

    const int tid  = threadIdx.x;
    const int wv   = tid >> 6;
    const int lane = tid & 63;
    const int hi   = lane >> 4;
    const int qr   = lane & 15;

    // XCD decode (R6-proven: FETCH 195->16MB) + balanced qt map (R7/R11)
    const int flat = (int)blockIdx.x;          // 0..1023
    const int xcd  = flat & 7;
    const int idx  = flat >> 3;
    const int bs   = idx >> 5;
    const int s    = idx & 31;
    const int bh   = xcd * 4 + bs;
    const int qt   = (bs & 1) ? s : (NQT - 1 - s);
    const int b    = bh >> 4;
    const int h    = bh & 15;
    const int q0   = qt * QBLK;

    const float LOG2E  = 1.4426950408889634f;
    const float slope2 = exp2f(-0.5f * (float)(h + 1)) * LOG2E;
    const float sc2    = 0.125f * LOG2E;
    float c2[16];
    #pragma unroll
    for (int st = 0; st < 4; ++st)
        #pragma unroll
        for (int rr = 0; rr < 4; ++rr) c2[st * 4 + rr] = (float)(st * 16 + rr) * slope2;

    // ---- Q fragments ----
    bf16x8 qf[2];
    {
        const float* gq = qg + ((size_t)(b * TT + q0 + wv * 16 + qr)) * DDIM + h * HD + hi * 8;
        #pragma unroll
        for (int ch = 0; ch < 2; ++ch) {
            float4 a0 = *(const float4*)(gq + ch * 32);
            float4 a1 = *(const float4*)(gq + ch * 32 + 4);
            bf16x8 w;
            w[0]=f2bf(a0.x); w[1]=f2bf(a0.y); w[2]=f2bf(a0.z); w[3]=f2bf(a0.w);
            w[4]=f2bf(a1.x); w[5]=f2bf(a1.y); w[6]=f2bf(a1.z); w[7]=f2bf(a1.w);
            qf[ch] = w;
        }
    }

    const ushort* kb = kbf + (size_t)bh * TT * HD;
    const ushort* vb = vt  + (size_t)bh * HD * TT;

    const int srow = tid >> 2;
    const int sci  = tid & 3;
    const int sw   = srow & 7;

    // incremental staging pointers (descending by KVBLK per issue)
    bf16x8 kr0, kr1, vr0, vr1;
    const ushort* kp = kb + (size_t)(q0 + srow) * HD + sci * 8;
    const ushort* vp = vb + (size_t)srow * TT + q0 + sci * 8;
    auto stage_issue = [&]() {
        kr0 = *(const bf16x8*)kp;  kr1 = *(const bf16x8*)(kp + 32);
        vr0 = *(const bf16x8*)vp;  vr1 = *(const bf16x8*)(vp + 32);
        kp -= (size_t)KVBLK * HD;  vp -= KVBLK;
    };
    auto stage_write = [&](int nb) {
        *(bf16x8*)&lds_k[nb][srow * 64 + ((sci ^ sw) << 3)]       = kr0;
        *(bf16x8*)&lds_k[nb][srow * 64 + (((sci + 4) ^ sw) << 3)] = kr1;
        *(bf16x8*)&lds_v[nb][srow * 64 + ((sci ^ sw) << 3)]       = vr0;
        *(bf16x8*)&lds_v[nb][srow * 64 + (((sci + 4) ^ sw) << 3)] = vr1;
    };

    const int nit = qt + 1;
    stage_issue();
    stage_write(0);

    f32x4 oacc[4] = {};
    float mrun = -INFINITY, lrun = 0.f;
    const int ti = q0 + wv * 16 + qr;

    for (int j = 0; j < nit; ++j) {
        const int buf = j & 1;
        const int kv0 = q0 - j * KVBLK;
        if (j + 1 < nit) stage_issue();   // loads stay in flight ACROSS the barrier
        barrier_lgkm_only();

        ushort* pb = &lds_v[buf ^ 1][wv * 1024];   // P aliased into idle V buffer
        const bool diag = (j == 0);

        // ---- S^T = K Q^T ----
        f32x4 sa[4] = {};
        __builtin_amdgcn_s_setprio(1);
        #pragma unroll
        for (int st = 0; st < 4; ++st) {
            if (!diag || st <= wv) {
                const int krow = st * 16 + qr;
                const int ksw = (krow & 7);
                bf16x8 k0 = *(const bf16x8*)&lds_k[buf][krow * 64 + ((hi ^ ksw) << 3)];
                bf16x8 k1 = *(const bf16x8*)&lds_k[buf][krow * 64 + (((4 + hi) ^ ksw) << 3)];
                sa[st] = __builtin_amdgcn_mfma_f32_16x16x32_bf16(k0, qf[0], sa[st], 0, 0, 0);
                sa[st] = __builtin_amdgcn_mfma_f32_16x16x32_bf16(k1, qf[1], sa[st], 0, 0, 0);
            }
        }
        __builtin_amdgcn_s_setprio(0);

        // ---- softmax: exact integer-domain causal mask (R9 lesson); hoisted c2;
        //      common path has NO cross-lane reduce (R12-validated) ----
        const float relb  = (float)(kv0 - ti + hi * 4);
        const float relb2 = relb * slope2;
        float xv[16];
        float tm = -INFINITY;
        #pragma unroll
        for (int st = 0; st < 4; ++st)
            #pragma unroll
            for (int rr = 0; rr < 4; ++rr) {
                float v = fmaf(sa[st][rr], sc2, relb2 + c2[st * 4 + rr]);
                if (diag) {
                    const float rel = relb + (float)(st * 16 + rr);   // exact small ints
                    v = (rel <= 0.f) ? v : -INFINITY;
                }
                xv[st * 4 + rr] = v;
                tm = fmaxf(tm, v);
            }
        if (!__all(tm <= mrun + 8.f)) {   // defer-max: rare after the diagonal
            tm = fmaxf(tm, __shfl_xor(tm, 16));
            tm = fmaxf(tm, __shfl_xor(tm, 32));
            const float mnew = fmaxf(mrun, tm);
            const float fsc  = exp2f(mrun - mnew);
            mrun = mnew;
            lrun *= fsc;
            float fo[4];
            #pragma unroll
            for (int rr = 0; rr < 4; ++rr) fo[rr] = __shfl(fsc, hi * 4 + rr);
            #pragma unroll
            for (int dt = 0; dt < 4; ++dt)
                #pragma unroll
                for (int rr = 0; rr < 4; ++rr) oacc[dt][rr] *= fo[rr];
        }
        float psum = 0.f;
        #pragma unroll
        for (int i = 0; i < 16; ++i) { xv[i] = exp2f(xv[i] - mrun); psum += xv[i]; }
        lrun += psum;

        // ---- P -> aliased LDS slot (same-wave producer/consumer) ----
        #pragma unroll
        for (int st = 0; st < 4; ++st) {
            ushort4 w;
            w.x = f2bf(xv[st * 4 + 0]); w.y = f2bf(xv[st * 4 + 1]);
            w.z = f2bf(xv[st * 4 + 2]); w.w = f2bf(xv[st * 4 + 3]);
            const int slot8 = (st << 1) | (hi >> 1);
            *(ushort4*)&pb[qr * 64 + ((slot8 ^ (qr & 7)) << 3) + ((hi & 1) << 2)] = w;
        }

        // ---- O += P V ----
        __builtin_amdgcn_s_setprio(1);
        #pragma unroll
        for (int ks = 0; ks < 2; ++ks) {
            if (!diag || wv >= 2 || ks == 0) {
                bf16x8 pa = *(const bf16x8*)&pb[qr * 64 + ((((ks << 2) | hi) ^ (qr & 7)) << 3)];
                #pragma unroll
                for (int dt = 0; dt < 4; ++dt) {
                    const int dv = dt * 16 + qr;
                    bf16x8 vbf = *(const bf16x8*)&lds_v[buf][dv * 64 + ((((ks << 2) + hi) ^ (dv & 7)) << 3)];
                    oacc[dt] = __builtin_amdgcn_mfma_f32_16x16x32_bf16(pa, vbf, oacc[dt], 0, 0, 0);
                }
            }
        }
        __builtin_amdgcn_s_setprio(0);

        if (j + 1 < nit) stage_write(buf ^ 1);   // overwrites this iter's P (safe);
                                                 // compiler's vmcnt wait lands here
    }

    // ---- epilogue ----
    {
        float lr = lrun;
        lr += __shfl_xor(lr, 16);
        lr += __shfl_xor(lr, 32);
        const float linv = 1.0f / lr;
        #pragma unroll
        for (int rr = 0; rr < 4; ++rr) {
            const float inv = __shfl(linv, hi * 4 + rr);
            float* go = out + ((size_t)(b * TT + q0 + wv * 16 + hi * 4 + rr)) * DDIM + h * HD;
            #pragma unroll
            for (int dt = 0; dt < 4; ++dt)
                go[dt * 16 + qr] = oacc[dt][rr] * inv;
        }
    }
}

// ============ fallback (R6 kernel, proven 76.5us) if ws too small ============
#define VST 72
__global__ __launch_bounds__(256, 2)
void alibi_attn_fallback(const float* __restrict__ qg,
                         const float* __restrict__ kg,
                         const float* __restrict__ vg,
                         float* __restrict__ out) {
    __shared__ __align__(16) ushort lds_k[KVBLK * HD];
    __shared__ __align__(16) ushort lds_vt[HD * VST];
    __shared__ __align__(16) ushort lds_p[4][16 * 64];

    const int tid  = threadIdx.x;
    const int wv   = tid >> 6;
    const int lane = tid & 63;
    const int hi   = lane >> 4;
    const int qr   = lane & 15;

    const int flat = (int)blockIdx.x;
    const int xcd  = flat & 7;
    const int idx  = flat >> 3;
    const int bh   = xcd * 4 + (idx >> 5);
    const int qt   = NQT - 1 - (idx & 31);
    const int b    = bh >> 4;
    const int h    = bh & 15;
    const int q0   = qt * QBLK;

    const float LOG2E  = 1.4426950408889634f;
    const float slope2 = exp2f(-0.5f * (float)(h + 1)) * LOG2E;
    const float sc2    = 0.125f * LOG2E;

    const size_t bhbase = (size_t)(b * TT) * DDIM + (size_t)(h * HD);

    bf16x8 qf[2];
    {
        const float* gq = qg + bhbase + (size_t)(q0 + wv * 16 + qr) * DDIM + hi * 8;
        #pragma unroll
        for (int ch = 0; ch < 2; ++ch) {
            float4 a0 = *(const float4*)(gq + ch * 32);
            float4 a1 = *(const float4*)(gq + ch * 32 + 4);
            bf16x8 w;
            w[0]=f2bf(a0.x); w[1]=f2bf(a0.y); w[2]=f2bf(a0.z); w[3]=f2bf(a0.w);
            w[4]=f2bf(a1.x); w[5]=f2bf(a1.y); w[6]=f2bf(a1.z); w[7]=f2bf(a1.w);
            qf[ch] = w;
        }
    }

    const int krow = tid >> 3;
    const int kcg  = tid & 7;
    const int vdv  = tid & 63;
    const int vkc  = tid >> 6;

    float ka[2][8], va[2][8];
    auto issue_loads = [&](int kv0) {
        const float* kp0 = kg + bhbase + (size_t)(kv0 + krow) * DDIM + kcg * 8;
        const float* kp1 = kp0 + (size_t)32 * DDIM;
        *(float4*)&ka[0][0] = *(const float4*)kp0; *(float4*)&ka[0][4] = *(const float4*)(kp0 + 4);
        *(float4*)&ka[1][0] = *(const float4*)kp1; *(float4*)&ka[1][4] = *(const float4*)(kp1 + 4);
        const float* vp0 = vg + bhbase + (size_t)(kv0 + vkc * 8) * DDIM + vdv;
        const float* vp1 = vp0 + (size_t)32 * DDIM;
        #pragma unroll
        for (int jj = 0; jj < 8; ++jj) {
            va[0][jj] = vp0[(size_t)jj * DDIM];
            va[1][jj] = vp1[(size_t)jj * DDIM];
        }
    };
    auto write_stage = [&]() {
        #pragma unroll
        for (int s2 = 0; s2 < 2; ++s2) {
            bf16x8 w;
            #pragma unroll
            for (int e = 0; e < 8; ++e) w[e] = f2bf(ka[s2][e]);
            const int row = krow + s2 * 32;
            *(bf16x8*)&lds_k[row * 64 + ((kcg ^ (row & 7)) << 3)] = w;
            bf16x8 u;
            #pragma unroll
            for (int e = 0; e < 8; ++e) u[e] = f2bf(va[s2][e]);
            const int kc = vkc + s2 * 4;
            *(bf16x8*)&lds_vt[vdv * VST + ((kc ^ ((vdv >> 3) & 7)) << 3)] = u;
        }
    };

    const int nit = qt + 1;
    issue_loads(q0);
    write_stage();

    f32x4 oacc[4] = {};
    float mrun = -INFINITY, lrun = 0.f;

    for (int j = 0; j < nit; ++j) {
        const int kv0 = (qt - j) * KVBLK;
        if (j + 1 < nit) issue_loads(kv0 - KVBLK);
        __syncthreads();

        const bool diag = (j == 0);

        f32x4 s_acc[4] = {};
        __builtin_amdgcn_s_setprio(1);
        #pragma unroll
        for (int st = 0; st < 4; ++st) {
            if (!diag || st <= wv) {
                const int kvrow = st * 16 + qr;
                #pragma unroll
                for (int ch = 0; ch < 2; ++ch) {
                    bf16x8 kf = *(const bf16x8*)&lds_k[kvrow * 64 + ((((ch << 2) + hi) ^ (kvrow & 7)) << 3)];
                    s_acc[st] = __builtin_amdgcn_mfma_f32_16x16x32_bf16(kf, qf[ch], s_acc[st], 0, 0, 0);
                }
            }
        }
        __builtin_amdgcn_s_setprio(0);

        const int ti = q0 + wv * 16 + qr;
        float xv[16];
        float tm = -INFINITY;
        {
            const float relb = (float)(kv0 - ti);
            #pragma unroll
            for (int st = 0; st < 4; ++st)
                #pragma unroll
                for (int rr = 0; rr < 4; ++rr) {
                    const float rel = relb + (float)(st * 16 + hi * 4 + rr);
                    float v = s_acc[st][rr] * sc2 + rel * slope2;
                    if (diag) v = (rel <= 0.f) ? v : -INFINITY;
                    xv[st * 4 + rr] = v;
                    tm = fmaxf(tm, v);
                }
        }
        tm = fmaxf(tm, __shfl_xor(tm, 16));
        tm = fmaxf(tm, __shfl_xor(tm, 32));
        if (!__all(tm <= mrun + 8.f)) {
            const float mnew = fmaxf(mrun, tm);
            const float fsc  = exp2f(mrun - mnew);
            mrun = mnew;
            lrun *= fsc;
            float fo[4];
            #pragma unroll
            for (int rr = 0; rr < 4; ++rr) fo[rr] = __shfl(fsc, hi * 4 + rr);
            #pragma unroll
            for (int dt = 0; dt < 4; ++dt)
                #pragma unroll
                for (int rr = 0; rr < 4; ++rr) oacc[dt][rr] *= fo[rr];
        }
        float psum = 0.f;
        #pragma unroll
        for (int i = 0; i < 16; ++i) { xv[i] = exp2f(xv[i] - mrun); psum += xv[i]; }
        lrun += psum;

        #pragma unroll
        for (int st = 0; st < 4; ++st) {
            ushort4 w;
            w.x = f2bf(xv[st * 4 + 0]); w.y = f2bf(xv[st * 4 + 1]);
            w.z = f2bf(xv[st * 4 + 2]); w.w = f2bf(xv[st * 4 + 3]);
            const int slot8 = (st << 1) | (hi >> 1);
            *(ushort4*)&lds_p[wv][qr * 64 + ((slot8 ^ (qr & 7)) << 3) + ((hi & 1) << 2)] = w;
        }

        __builtin_amdgcn_s_setprio(1);
        #pragma unroll
        for (int ks = 0; ks < 2; ++ks) {
            if (!diag || wv >= 2 || ks == 0) {
                bf16x8 pa = *(const bf16x8*)&lds_p[wv][qr * 64 + ((((ks << 2) | hi) ^ (qr & 7)) << 3)];
                #pragma unroll
                for (int dt = 0; dt < 4; ++dt) {
                    const int dv = dt * 16 + qr;
                    bf16x8 vbf = *(const bf16x8*)&lds_vt[dv * VST + ((((ks << 2) + hi) ^ ((dv >> 3) & 7)) << 3)];
                    oacc[dt] = __builtin_amdgcn_mfma_f32_16x16x32_bf16(pa, vbf, oacc[dt], 0, 0, 0);
                }
            }
        }
        __builtin_amdgcn_s_setprio(0);

        if (j + 1 < nit) {
            __syncthreads();
            write_stage();
        }
    }

    {
        float lr = lrun;
        lr += __shfl_xor(lr, 16);
        lr += __shfl_xor(lr, 32);
        const float linv = 1.0f / lr;
        #pragma unroll
        for (int rr = 0; rr < 4; ++rr) {
            const float inv = __shfl(linv, hi * 4 + rr);
            float* go = out + bhbase + (size_t)(q0 + wv * 16 + hi * 4 + rr) * DDIM;
            #pragma unroll
            for (int dt = 0; dt < 4; ++dt)
                go[dt * 16 + qr] = oacc[dt][rr] * inv;
        }
    }
}

extern "C" void kernel_launch(void* const* d_in, const int* in_sizes, int n_in,
                              void* d_out, int out_size, void* d_ws, size_t ws_size,
                              hipStream_t stream) {
    (void)in_sizes; (void)n_in; (void)out_size;
    const float* q = (const float*)d_in[0];
    const float* k = (const float*)d_in[1];
    const float* v = (const float*)d_in[2];
    float* o = (float*)d_out;

    const size_t elems = (size_t)2 * NHEAD * TT * HD;
    const size_t kv_b  = 2 * elems * sizeof(ushort);       // 16.78 MB
    if (ws_size >= kv_b) {
        ushort* kbf = (ushort*)d_ws;
        ushort* vtt = kbf + elems;
        prepass_kernel<<<dim3(32, 32), 256, 0, stream>>>(k, v, kbf, vtt);
        attn_main<<<dim3(1024), 256, 0, stream>>>(q, kbf, vtt, o);
    } else {
        alibi_attn_fallback<<<dim3(1024), 256, 0, stream>>>(q, k, v, o);
    }
}

// Round 22
// 61.265 us; speedup vs baseline: 1.1873x; 1.0071x over previous
//
#include <hip/hip_runtime.h>
#include <hip/hip_bf16.h>

#define TT 2048
#define DDIM 1024
#define NHEAD 16
#define HD 64
#define QBLK 64
#define KVBLK 64
#define NQT (TT / QBLK)

typedef float f32x4 __attribute__((ext_vector_type(4)));
typedef short bf16x8 __attribute__((ext_vector_type(8)));

__device__ __forceinline__ ushort f2bf(float f) {
    __hip_bfloat16 h = __float2bfloat16(f);
    return *reinterpret_cast<ushort*>(&h);
}

// Counted-wait barrier, HARDENED (R17 lesson): s_barrier has NO memory/motion
// semantics in LLVM — sched_barrier(0) on both sides stops ds_reads hoisting
// above it (cross-wave race). lgkmcnt(0) drains this wave's LDS writes;
// prefetch global loads stay in flight (no vmcnt drain — R11's +22us lever).
__device__ __forceinline__ void barrier_lgkm_only() {
    __builtin_amdgcn_sched_barrier(0);
    asm volatile("s_waitcnt lgkmcnt(0)" ::: "memory");
    __builtin_amdgcn_s_barrier();
    __builtin_amdgcn_sched_barrier(0);
}

// ============ pre-pass (R8-proven): K -> bf16, V -> bf16 transposed ============
__global__ __launch_bounds__(256)
void prepass_kernel(const float* __restrict__ kg, const float* __restrict__ vg,
                    ushort* __restrict__ kbf, ushort* __restrict__ vt) {
    __shared__ float vtile[64][65];
    const int tid = threadIdx.x;
    const int kv0 = (int)blockIdx.x * 64;
    const int bh  = (int)blockIdx.y;
    const int b = bh >> 4, h = bh & 15;
    const int row = tid >> 2;
    const int c0  = (tid & 3) * 16;
    const size_t gin = ((size_t)(b * TT + kv0 + row)) * DDIM + h * HD + c0;
    {
        ushort o[16];
        #pragma unroll
        for (int i = 0; i < 4; ++i) {
            float4 a = *(const float4*)(kg + gin + i * 4);
            o[i*4+0]=f2bf(a.x); o[i*4+1]=f2bf(a.y); o[i*4+2]=f2bf(a.z); o[i*4+3]=f2bf(a.w);
        }
        ushort* kout = kbf + ((size_t)bh * TT + kv0 + row) * HD + c0;
        *(bf16x8*)kout       = *(bf16x8*)&o[0];
        *(bf16x8*)(kout + 8) = *(bf16x8*)&o[8];
    }
    #pragma unroll
    for (int i = 0; i < 4; ++i) {
        float4 a = *(const float4*)(vg + gin + i * 4);
        vtile[row][c0 + i*4 + 0] = a.x;
        vtile[row][c0 + i*4 + 1] = a.y;
        vtile[row][c0 + i*4 + 2] = a.z;
        vtile[row][c0 + i*4 + 3] = a.w;
    }
    __syncthreads();
    {
        ushort o[16];
        #pragma unroll
        for (int i = 0; i < 16; ++i) o[i] = f2bf(vtile[c0 + i][row]);
        ushort* vout = vt + ((size_t)bh * HD + row) * TT + kv0 + c0;
        *(bf16x8*)vout       = *(bf16x8*)&o[0];
        *(bf16x8*)(vout + 8) = *(bf16x8*)&o[8];
    }
}

// ============ main: R19 structure, setprio REMOVED (T5 A/B) ============
// T5 is structure-conditional: +4-7% on independent-block attn (m191) but
// NEGATIVE on barrier-lockstep structures (m190). Our waves are lockstep
// within a block — this A/B decides. Everything else identical to R19/R21.
__global__ __launch_bounds__(256, 2)
void attn_main(const float* __restrict__ qg, const ushort* __restrict__ kbf,
               const ushort* __restrict__ vt, float* __restrict__ out) {
    __shared__ __align__(16) ushort lds_k[2][KVBLK * HD];
    __shared__ __align__(16) ushort lds_v[2][HD * KVBLK];

    const int tid  = threadIdx.x;
    const int wv   = tid >> 6;
    const int lane = tid & 63;
    const int hi   = lane >> 4;
    const int qr   = lane & 15;

    // XCD decode (R6-proven: FETCH 195->16MB) + balanced qt map (R7/R11)
    const int flat = (int)blockIdx.x;          // 0..1023
    const int xcd  = flat & 7;
    const int idx  = flat >> 3;
    const int bs   = idx >> 5;
    const int s    = idx & 31;
    const int bh   = xcd * 4 + bs;
    const int qt   = (bs & 1) ? s : (NQT - 1 - s);
    const int b    = bh >> 4;
    const int h    = bh & 15;
    const int q0   = qt * QBLK;

    const float LOG2E  = 1.4426950408889634f;
    const float slope2 = exp2f(-0.5f * (float)(h + 1)) * LOG2E;
    const float sc2    = 0.125f * LOG2E;
    float c2[16];
    #pragma unroll
    for (int st = 0; st < 4; ++st)
        #pragma unroll
        for (int rr = 0; rr < 4; ++rr) c2[st * 4 + rr] = (float)(st * 16 + rr) * slope2;

    // ---- Q fragments ----
    bf16x8 qf[2];
    {
        const float* gq = qg + ((size_t)(b * TT + q0 + wv * 16 + qr)) * DDIM + h * HD + hi * 8;
        #pragma unroll
        for (int ch = 0; ch < 2; ++ch) {
            float4 a0 = *(const float4*)(gq + ch * 32);
            float4 a1 = *(const float4*)(gq + ch * 32 + 4);
            bf16x8 w;
            w[0]=f2bf(a0.x); w[1]=f2bf(a0.y); w[2]=f2bf(a0.z); w[3]=f2bf(a0.w);
            w[4]=f2bf(a1.x); w[5]=f2bf(a1.y); w[6]=f2bf(a1.z); w[7]=f2bf(a1.w);
            qf[ch] = w;
        }
    }

    const ushort* kb = kbf + (size_t)bh * TT * HD;
    const ushort* vb = vt  + (size_t)bh * HD * TT;

    const int srow = tid >> 2;
    const int sci  = tid & 3;
    const int sw   = srow & 7;

    // incremental staging pointers (descending by KVBLK per issue)
    bf16x8 kr0, kr1, vr0, vr1;
    const ushort* kp = kb + (size_t)(q0 + srow) * HD + sci * 8;
    const ushort* vp = vb + (size_t)srow * TT + q0 + sci * 8;
    auto stage_issue = [&]() {
        kr0 = *(const bf16x8*)kp;  kr1 = *(const bf16x8*)(kp + 32);
        vr0 = *(const bf16x8*)vp;  vr1 = *(const bf16x8*)(vp + 32);
        kp -= (size_t)KVBLK * HD;  vp -= KVBLK;
    };
    auto stage_write = [&](int nb) {
        *(bf16x8*)&lds_k[nb][srow * 64 + ((sci ^ sw) << 3)]       = kr0;
        *(bf16x8*)&lds_k[nb][srow * 64 + (((sci + 4) ^ sw) << 3)] = kr1;
        *(bf16x8*)&lds_v[nb][srow * 64 + ((sci ^ sw) << 3)]       = vr0;
        *(bf16x8*)&lds_v[nb][srow * 64 + (((sci + 4) ^ sw) << 3)] = vr1;
    };

    const int nit = qt + 1;
    stage_issue();
    stage_write(0);

    f32x4 oacc[4] = {};
    float mrun = -INFINITY, lrun = 0.f;
    const int ti = q0 + wv * 16 + qr;

    for (int j = 0; j < nit; ++j) {
        const int buf = j & 1;
        const int kv0 = q0 - j * KVBLK;
        if (j + 1 < nit) stage_issue();   // loads stay in flight ACROSS the barrier
        barrier_lgkm_only();

        ushort* pb = &lds_v[buf ^ 1][wv * 1024];   // P aliased into idle V buffer
        const bool diag = (j == 0);

        // ---- S^T = K Q^T ----
        f32x4 sa[4] = {};
        #pragma unroll
        for (int st = 0; st < 4; ++st) {
            if (!diag || st <= wv) {
                const int krow = st * 16 + qr;
                const int ksw = (krow & 7);
                bf16x8 k0 = *(const bf16x8*)&lds_k[buf][krow * 64 + ((hi ^ ksw) << 3)];
                bf16x8 k1 = *(const bf16x8*)&lds_k[buf][krow * 64 + (((4 + hi) ^ ksw) << 3)];
                sa[st] = __builtin_amdgcn_mfma_f32_16x16x32_bf16(k0, qf[0], sa[st], 0, 0, 0);
                sa[st] = __builtin_amdgcn_mfma_f32_16x16x32_bf16(k1, qf[1], sa[st], 0, 0, 0);
            }
        }

        // ---- softmax: exact integer-domain causal mask (R9 lesson); hoisted c2;
        //      common path has NO cross-lane reduce (R12-validated) ----
        const float relb  = (float)(kv0 - ti + hi * 4);
        const float relb2 = relb * slope2;
        float xv[16];
        float tm = -INFINITY;
        #pragma unroll
        for (int st = 0; st < 4; ++st)
            #pragma unroll
            for (int rr = 0; rr < 4; ++rr) {
                float v = fmaf(sa[st][rr], sc2, relb2 + c2[st * 4 + rr]);
                if (diag) {
                    const float rel = relb + (float)(st * 16 + rr);   // exact small ints
                    v = (rel <= 0.f) ? v : -INFINITY;
                }
                xv[st * 4 + rr] = v;
                tm = fmaxf(tm, v);
            }
        if (!__all(tm <= mrun + 8.f)) {   // defer-max: rare after the diagonal
            tm = fmaxf(tm, __shfl_xor(tm, 16));
            tm = fmaxf(tm, __shfl_xor(tm, 32));
            const float mnew = fmaxf(mrun, tm);
            const float fsc  = exp2f(mrun - mnew);
            mrun = mnew;
            lrun *= fsc;
            float fo[4];
            #pragma unroll
            for (int rr = 0; rr < 4; ++rr) fo[rr] = __shfl(fsc, hi * 4 + rr);
            #pragma unroll
            for (int dt = 0; dt < 4; ++dt)
                #pragma unroll
                for (int rr = 0; rr < 4; ++rr) oacc[dt][rr] *= fo[rr];
        }
        float psum = 0.f;
        #pragma unroll
        for (int i = 0; i < 16; ++i) { xv[i] = exp2f(xv[i] - mrun); psum += xv[i]; }
        lrun += psum;

        // ---- P -> aliased LDS slot (same-wave producer/consumer) ----
        #pragma unroll
        for (int st = 0; st < 4; ++st) {
            ushort4 w;
            w.x = f2bf(xv[st * 4 + 0]); w.y = f2bf(xv[st * 4 + 1]);
            w.z = f2bf(xv[st * 4 + 2]); w.w = f2bf(xv[st * 4 + 3]);
            const int slot8 = (st << 1) | (hi >> 1);
            *(ushort4*)&pb[qr * 64 + ((slot8 ^ (qr & 7)) << 3) + ((hi & 1) << 2)] = w;
        }

        // ---- O += P V ----
        #pragma unroll
        for (int ks = 0; ks < 2; ++ks) {
            if (!diag || wv >= 2 || ks == 0) {
                bf16x8 pa = *(const bf16x8*)&pb[qr * 64 + ((((ks << 2) | hi) ^ (qr & 7)) << 3)];
                #pragma unroll
                for (int dt = 0; dt < 4; ++dt) {
                    const int dv = dt * 16 + qr;
                    bf16x8 vbf = *(const bf16x8*)&lds_v[buf][dv * 64 + ((((ks << 2) + hi) ^ (dv & 7)) << 3)];
                    oacc[dt] = __builtin_amdgcn_mfma_f32_16x16x32_bf16(pa, vbf, oacc[dt], 0, 0, 0);
                }
            }
        }

        if (j + 1 < nit) stage_write(buf ^ 1);   // overwrites this iter's P (safe);
                                                 // compiler's vmcnt wait lands here
    }

    // ---- epilogue ----
    {
        float lr = lrun;
        lr += __shfl_xor(lr, 16);
        lr += __shfl_xor(lr, 32);
        const float linv = 1.0f / lr;
        #pragma unroll
        for (int rr = 0; rr < 4; ++rr) {
            const float inv = __shfl(linv, hi * 4 + rr);
            float* go = out + ((size_t)(b * TT + q0 + wv * 16 + hi * 4 + rr)) * DDIM + h * HD;
            #pragma unroll
            for (int dt = 0; dt < 4; ++dt)
                go[dt * 16 + qr] = oacc[dt][rr] * inv;
        }
    }
}

// ============ fallback (R6 kernel, proven 76.5us) if ws too small ============
#define VST 72
__global__ __launch_bounds__(256, 2)
void alibi_attn_fallback(const float* __restrict__ qg,
                         const float* __restrict__ kg,
                         const float* __restrict__ vg,
                         float* __restrict__ out) {
    __shared__ __align__(16) ushort lds_k[KVBLK * HD];
    __shared__ __align__(16) ushort lds_vt[HD * VST];
    __shared__ __align__(16) ushort lds_p[4][16 * 64];

    const int tid  = threadIdx.x;
    const int wv   = tid >> 6;
    const int lane = tid & 63;
    const int hi   = lane >> 4;
    const int qr   = lane & 15;

    const int flat = (int)blockIdx.x;
    const int xcd  = flat & 7;
    const int idx  = flat >> 3;
    const int bh   = xcd * 4 + (idx >> 5);
    const int qt   = NQT - 1 - (idx & 31);
    const int b    = bh >> 4;
    const int h    = bh & 15;
    const int q0   = qt * QBLK;

    const float LOG2E  = 1.4426950408889634f;
    const float slope2 = exp2f(-0.5f * (float)(h + 1)) * LOG2E;
    const float sc2    = 0.125f * LOG2E;

    const size_t bhbase = (size_t)(b * TT) * DDIM + (size_t)(h * HD);

    bf16x8 qf[2];
    {
        const float* gq = qg + bhbase + (size_t)(q0 + wv * 16 + qr) * DDIM + hi * 8;
        #pragma unroll
        for (int ch = 0; ch < 2; ++ch) {
            float4 a0 = *(const float4*)(gq + ch * 32);
            float4 a1 = *(const float4*)(gq + ch * 32 + 4);
            bf16x8 w;
            w[0]=f2bf(a0.x); w[1]=f2bf(a0.y); w[2]=f2bf(a0.z); w[3]=f2bf(a0.w);
            w[4]=f2bf(a1.x); w[5]=f2bf(a1.y); w[6]=f2bf(a1.z); w[7]=f2bf(a1.w);
            qf[ch] = w;
        }
    }

    const int krow = tid >> 3;
    const int kcg  = tid & 7;
    const int vdv  = tid & 63;
    const int vkc  = tid >> 6;

    float ka[2][8], va[2][8];
    auto issue_loads = [&](int kv0) {
        const float* kp0 = kg + bhbase + (size_t)(kv0 + krow) * DDIM + kcg * 8;
        const float* kp1 = kp0 + (size_t)32 * DDIM;
        *(float4*)&ka[0][0] = *(const float4*)kp0; *(float4*)&ka[0][4] = *(const float4*)(kp0 + 4);
        *(float4*)&ka[1][0] = *(const float4*)kp1; *(float4*)&ka[1][4] = *(const float4*)(kp1 + 4);
        const float* vp0 = vg + bhbase + (size_t)(kv0 + vkc * 8) * DDIM + vdv;
        const float* vp1 = vp0 + (size_t)32 * DDIM;
        #pragma unroll
        for (int jj = 0; jj < 8; ++jj) {
            va[0][jj] = vp0[(size_t)jj * DDIM];
            va[1][jj] = vp1[(size_t)jj * DDIM];
        }
    };
    auto write_stage = [&]() {
        #pragma unroll
        for (int s2 = 0; s2 < 2; ++s2) {
            bf16x8 w;
            #pragma unroll
            for (int e = 0; e < 8; ++e) w[e] = f2bf(ka[s2][e]);
            const int row = krow + s2 * 32;
            *(bf16x8*)&lds_k[row * 64 + ((kcg ^ (row & 7)) << 3)] = w;
            bf16x8 u;
            #pragma unroll
            for (int e = 0; e < 8; ++e) u[e] = f2bf(va[s2][e]);
            const int kc = vkc + s2 * 4;
            *(bf16x8*)&lds_vt[vdv * VST + ((kc ^ ((vdv >> 3) & 7)) << 3)] = u;
        }
    };

    const int nit = qt + 1;
    issue_loads(q0);
    write_stage();

    f32x4 oacc[4] = {};
    float mrun = -INFINITY, lrun = 0.f;

    for (int j = 0; j < nit; ++j) {
        const int kv0 = (qt - j) * KVBLK;
        if (j + 1 < nit) issue_loads(kv0 - KVBLK);
        __syncthreads();

        const bool diag = (j == 0);

        f32x4 s_acc[4] = {};
        #pragma unroll
        for (int st = 0; st < 4; ++st) {
            if (!diag || st <= wv) {
                const int kvrow = st * 16 + qr;
                #pragma unroll
                for (int ch = 0; ch < 2; ++ch) {
                    bf16x8 kf = *(const bf16x8*)&lds_k[kvrow * 64 + ((((ch << 2) + hi) ^ (kvrow & 7)) << 3)];
                    s_acc[st] = __builtin_amdgcn_mfma_f32_16x16x32_bf16(kf, qf[ch], s_acc[st], 0, 0, 0);
                }
            }
        }

        const int ti = q0 + wv * 16 + qr;
        float xv[16];
        float tm = -INFINITY;
        {
            const float relb = (float)(kv0 - ti);
            #pragma unroll
            for (int st = 0; st < 4; ++st)
                #pragma unroll
                for (int rr = 0; rr < 4; ++rr) {
                    const float rel = relb + (float)(st * 16 + hi * 4 + rr);
                    float v = s_acc[st][rr] * sc2 + rel * slope2;
                    if (diag) v = (rel <= 0.f) ? v : -INFINITY;
                    xv[st * 4 + rr] = v;
                    tm = fmaxf(tm, v);
                }
        }
        tm = fmaxf(tm, __shfl_xor(tm, 16));
        tm = fmaxf(tm, __shfl_xor(tm, 32));
        if (!__all(tm <= mrun + 8.f)) {
            const float mnew = fmaxf(mrun, tm);
            const float fsc  = exp2f(mrun - mnew);
            mrun = mnew;
            lrun *= fsc;
            float fo[4];
            #pragma unroll
            for (int rr = 0; rr < 4; ++rr) fo[rr] = __shfl(fsc, hi * 4 + rr);
            #pragma unroll
            for (int dt = 0; dt < 4; ++dt)
                #pragma unroll
                for (int rr = 0; rr < 4; ++rr) oacc[dt][rr] *= fo[rr];
        }
        float psum = 0.f;
        #pragma unroll
        for (int i = 0; i < 16; ++i) { xv[i] = exp2f(xv[i] - mrun); psum += xv[i]; }
        lrun += psum;

        #pragma unroll
        for (int st = 0; st < 4; ++st) {
            ushort4 w;
            w.x = f2bf(xv[st * 4 + 0]); w.y = f2bf(xv[st * 4 + 1]);
            w.z = f2bf(xv[st * 4 + 2]); w.w = f2bf(xv[st * 4 + 3]);
            const int slot8 = (st << 1) | (hi >> 1);
            *(ushort4*)&lds_p[wv][qr * 64 + ((slot8 ^ (qr & 7)) << 3) + ((hi & 1) << 2)] = w;
        }

        #pragma unroll
        for (int ks = 0; ks < 2; ++ks) {
            if (!diag || wv >= 2 || ks == 0) {
                bf16x8 pa = *(const bf16x8*)&lds_p[wv][qr * 64 + ((((ks << 2) | hi) ^ (qr & 7)) << 3)];
                #pragma unroll
                for (int dt = 0; dt < 4; ++dt) {
                    const int dv = dt * 16 + qr;
                    bf16x8 vbf = *(const bf16x8*)&lds_vt[dv * VST + ((((ks << 2) + hi) ^ ((dv >> 3) & 7)) << 3)];
                    oacc[dt] = __builtin_amdgcn_mfma_f32_16x16x32_bf16(pa, vbf, oacc[dt], 0, 0, 0);
                }
            }
        }

        if (j + 1 < nit) {
            __syncthreads();
            write_stage();
        }
    }

    {
        float lr = lrun;
        lr += __shfl_xor(lr, 16);
        lr += __shfl_xor(lr, 32);
        const float linv = 1.0f / lr;
        #pragma unroll
        for (int rr = 0; rr < 4; ++rr) {
            const float inv = __shfl(linv, hi * 4 + rr);
            float* go = out + bhbase + (size_t)(q0 + wv * 16 + hi * 4 + rr) * DDIM;
            #pragma unroll
            for (int dt = 0; dt < 4; ++dt)
                go[dt * 16 + qr] = oacc[dt][rr] * inv;
        }
    }
}

extern "C" void kernel_launch(void* const* d_in, const int* in_sizes, int n_in,
                              void* d_out, int out_size, void* d_ws, size_t ws_size,
                              hipStream_t stream) {
    (void)in_sizes; (void)n_in; (void)out_size;
    const float* q = (const float*)d_in[0];
    const float* k = (const float*)d_in[1];
    const float* v = (const float*)d_in[2];
    float* o = (float*)d_out;

    const size_t elems = (size_t)2 * NHEAD * TT * HD;
    const size_t kv_b  = 2 * elems * sizeof(ushort);       // 16.78 MB
    if (ws_size >= kv_b) {
        ushort* kbf = (ushort*)d_ws;
        ushort* vtt = kbf + elems;
        prepass_kernel<<<dim3(32, 32), 256, 0, stream>>>(k, v, kbf, vtt);
        attn_main<<<dim3(1024), 256, 0, stream>>>(q, kbf, vtt, o);
    } else {
        alibi_attn_fallback<<<dim3(1024), 256, 0, stream>>>(q, k, v, o);
    }
}

// Round 23
// 61.072 us; speedup vs baseline: 1.1910x; 1.0032x over previous
//
#include <hip/hip_runtime.h>
#include <hip/hip_bf16.h>

// ============================================================================
// FINAL (R23 = R22 confirmed): MultiHeadAlibiAttention, MI355X gfx950.
// 243.9us (R1 naive MFMA flash) -> 61.3us. Structure:
//   prepass: K->bf16 copy + V->bf16-transpose into d_ws (~3.5us)
//   main: 64-row q-tiles, 4 waves, swapped QK^T (S^T via mfma(K,Q)) =>
//         in-register softmax; K/V dbuf LDS + depth-1 reg prefetch with
//         counted lgkm-only barrier (loads in flight ACROSS barrier, +35%);
//         P aliased into idle V-buffer (32KB LDS); exact integer-domain
//         causal mask; defer-max; XCD-local bh decode (FETCH 195->16MB).
// Falsified levers: balance remaps, kv-split, V-from-L2, depth-2 prefetch,
// QBLK=128, 32x32 MFMA, softmax peel/fold, setprio. Plateau is the 2-barrier
// schedule's issue+dependency structure (~2250cyc/block-iter), not a HW
// roofline; next step would be a full CK-style 8-phase counted-vmcnt rewrite.
// ============================================================================

#define TT 2048
#define DDIM 1024
#define NHEAD 16
#define HD 64
#define QBLK 64
#define KVBLK 64
#define NQT (TT / QBLK)

typedef float f32x4 __attribute__((ext_vector_type(4)));
typedef short bf16x8 __attribute__((ext_vector_type(8)));

__device__ __forceinline__ ushort f2bf(float f) {
    __hip_bfloat16 h = __float2bfloat16(f);
    return *reinterpret_cast<ushort*>(&h);
}

// Counted-wait barrier, HARDENED (R17 lesson): s_barrier has NO memory/motion
// semantics in LLVM — sched_barrier(0) on both sides stops ds_reads hoisting
// above it (cross-wave race). lgkmcnt(0) drains this wave's LDS writes;
// prefetch global loads stay in flight (no vmcnt drain — R11's +22us lever).
__device__ __forceinline__ void barrier_lgkm_only() {
    __builtin_amdgcn_sched_barrier(0);
    asm volatile("s_waitcnt lgkmcnt(0)" ::: "memory");
    __builtin_amdgcn_s_barrier();
    __builtin_amdgcn_sched_barrier(0);
}

// ============ pre-pass (R8-proven): K -> bf16, V -> bf16 transposed ============
__global__ __launch_bounds__(256)
void prepass_kernel(const float* __restrict__ kg, const float* __restrict__ vg,
                    ushort* __restrict__ kbf, ushort* __restrict__ vt) {
    __shared__ float vtile[64][65];
    const int tid = threadIdx.x;
    const int kv0 = (int)blockIdx.x * 64;
    const int bh  = (int)blockIdx.y;
    const int b = bh >> 4, h = bh & 15;
    const int row = tid >> 2;
    const int c0  = (tid & 3) * 16;
    const size_t gin = ((size_t)(b * TT + kv0 + row)) * DDIM + h * HD + c0;
    {
        ushort o[16];
        #pragma unroll
        for (int i = 0; i < 4; ++i) {
            float4 a = *(const float4*)(kg + gin + i * 4);
            o[i*4+0]=f2bf(a.x); o[i*4+1]=f2bf(a.y); o[i*4+2]=f2bf(a.z); o[i*4+3]=f2bf(a.w);
        }
        ushort* kout = kbf + ((size_t)bh * TT + kv0 + row) * HD + c0;
        *(bf16x8*)kout       = *(bf16x8*)&o[0];
        *(bf16x8*)(kout + 8) = *(bf16x8*)&o[8];
    }
    #pragma unroll
    for (int i = 0; i < 4; ++i) {
        float4 a = *(const float4*)(vg + gin + i * 4);
        vtile[row][c0 + i*4 + 0] = a.x;
        vtile[row][c0 + i*4 + 1] = a.y;
        vtile[row][c0 + i*4 + 2] = a.z;
        vtile[row][c0 + i*4 + 3] = a.w;
    }
    __syncthreads();
    {
        ushort o[16];
        #pragma unroll
        for (int i = 0; i < 16; ++i) o[i] = f2bf(vtile[c0 + i][row]);
        ushort* vout = vt + ((size_t)bh * HD + row) * TT + kv0 + c0;
        *(bf16x8*)vout       = *(bf16x8*)&o[0];
        *(bf16x8*)(vout + 8) = *(bf16x8*)&o[8];
    }
}

// ============ main: converged kernel (R19 structure, setprio-free) ============
__global__ __launch_bounds__(256, 2)
void attn_main(const float* __restrict__ qg, const ushort* __restrict__ kbf,
               const ushort* __restrict__ vt, float* __restrict__ out) {
    __shared__ __align__(16) ushort lds_k[2][KVBLK * HD];
    __shared__ __align__(16) ushort lds_v[2][HD * KVBLK];

    const int tid  = threadIdx.x;
    const int wv   = tid >> 6;
    const int lane = tid & 63;
    const int hi   = lane >> 4;
    const int qr   = lane & 15;

    // XCD decode (R6-proven: FETCH 195->16MB) + balanced qt map (R7/R11)
    const int flat = (int)blockIdx.x;          // 0..1023
    const int xcd  = flat & 7;
    const int idx  = flat >> 3;
    const int bs   = idx >> 5;
    const int s    = idx & 31;
    const int bh   = xcd * 4 + bs;
    const int qt   = (bs & 1) ? s : (NQT - 1 - s);
    const int b    = bh >> 4;
    const int h    = bh & 15;
    const int q0   = qt * QBLK;

    const float LOG2E  = 1.4426950408889634f;
    const float slope2 = exp2f(-0.5f * (float)(h + 1)) * LOG2E;
    const float sc2    = 0.125f * LOG2E;
    float c2[16];
    #pragma unroll
    for (int st = 0; st < 4; ++st)
        #pragma unroll
        for (int rr = 0; rr < 4; ++rr) c2[st * 4 + rr] = (float)(st * 16 + rr) * slope2;

    // ---- Q fragments ----
    bf16x8 qf[2];
    {
        const float* gq = qg + ((size_t)(b * TT + q0 + wv * 16 + qr)) * DDIM + h * HD + hi * 8;
        #pragma unroll
        for (int ch = 0; ch < 2; ++ch) {
            float4 a0 = *(const float4*)(gq + ch * 32);
            float4 a1 = *(const float4*)(gq + ch * 32 + 4);
            bf16x8 w;
            w[0]=f2bf(a0.x); w[1]=f2bf(a0.y); w[2]=f2bf(a0.z); w[3]=f2bf(a0.w);
            w[4]=f2bf(a1.x); w[5]=f2bf(a1.y); w[6]=f2bf(a1.z); w[7]=f2bf(a1.w);
            qf[ch] = w;
        }
    }

    const ushort* kb = kbf + (size_t)bh * TT * HD;
    const ushort* vb = vt  + (size_t)bh * HD * TT;

    const int srow = tid >> 2;
    const int sci  = tid & 3;
    const int sw   = srow & 7;

    // incremental staging pointers (descending by KVBLK per issue)
    bf16x8 kr0, kr1, vr0, vr1;
    const ushort* kp = kb + (size_t)(q0 + srow) * HD + sci * 8;
    const ushort* vp = vb + (size_t)srow * TT + q0 + sci * 8;
    auto stage_issue = [&]() {
        kr0 = *(const bf16x8*)kp;  kr1 = *(const bf16x8*)(kp + 32);
        vr0 = *(const bf16x8*)vp;  vr1 = *(const bf16x8*)(vp + 32);
        kp -= (size_t)KVBLK * HD;  vp -= KVBLK;
    };
    auto stage_write = [&](int nb) {
        *(bf16x8*)&lds_k[nb][srow * 64 + ((sci ^ sw) << 3)]       = kr0;
        *(bf16x8*)&lds_k[nb][srow * 64 + (((sci + 4) ^ sw) << 3)] = kr1;
        *(bf16x8*)&lds_v[nb][srow * 64 + ((sci ^ sw) << 3)]       = vr0;
        *(bf16x8*)&lds_v[nb][srow * 64 + (((sci + 4) ^ sw) << 3)] = vr1;
    };

    const int nit = qt + 1;
    stage_issue();
    stage_write(0);

    f32x4 oacc[4] = {};
    float mrun = -INFINITY, lrun = 0.f;
    const int ti = q0 + wv * 16 + qr;

    for (int j = 0; j < nit; ++j) {
        const int buf = j & 1;
        const int kv0 = q0 - j * KVBLK;
        if (j + 1 < nit) stage_issue();   // loads stay in flight ACROSS the barrier
        barrier_lgkm_only();

        ushort* pb = &lds_v[buf ^ 1][wv * 1024];   // P aliased into idle V buffer
        const bool diag = (j == 0);

        // ---- S^T = K Q^T ----
        f32x4 sa[4] = {};
        #pragma unroll
        for (int st = 0; st < 4; ++st) {
            if (!diag || st <= wv) {
                const int krow = st * 16 + qr;
                const int ksw = (krow & 7);
                bf16x8 k0 = *(const bf16x8*)&lds_k[buf][krow * 64 + ((hi ^ ksw) << 3)];
                bf16x8 k1 = *(const bf16x8*)&lds_k[buf][krow * 64 + (((4 + hi) ^ ksw) << 3)];
                sa[st] = __builtin_amdgcn_mfma_f32_16x16x32_bf16(k0, qf[0], sa[st], 0, 0, 0);
                sa[st] = __builtin_amdgcn_mfma_f32_16x16x32_bf16(k1, qf[1], sa[st], 0, 0, 0);
            }
        }

        // ---- softmax: exact integer-domain causal mask (R9 lesson); hoisted c2;
        //      common path has NO cross-lane reduce (R12-validated) ----
        const float relb  = (float)(kv0 - ti + hi * 4);
        const float relb2 = relb * slope2;
        float xv[16];
        float tm = -INFINITY;
        #pragma unroll
        for (int st = 0; st < 4; ++st)
            #pragma unroll
            for (int rr = 0; rr < 4; ++rr) {
                float v = fmaf(sa[st][rr], sc2, relb2 + c2[st * 4 + rr]);
                if (diag) {
                    const float rel = relb + (float)(st * 16 + rr);   // exact small ints
                    v = (rel <= 0.f) ? v : -INFINITY;
                }
                xv[st * 4 + rr] = v;
                tm = fmaxf(tm, v);
            }
        if (!__all(tm <= mrun + 8.f)) {   // defer-max: rare after the diagonal
            tm = fmaxf(tm, __shfl_xor(tm, 16));
            tm = fmaxf(tm, __shfl_xor(tm, 32));
            const float mnew = fmaxf(mrun, tm);
            const float fsc  = exp2f(mrun - mnew);
            mrun = mnew;
            lrun *= fsc;
            float fo[4];
            #pragma unroll
            for (int rr = 0; rr < 4; ++rr) fo[rr] = __shfl(fsc, hi * 4 + rr);
            #pragma unroll
            for (int dt = 0; dt < 4; ++dt)
                #pragma unroll
                for (int rr = 0; rr < 4; ++rr) oacc[dt][rr] *= fo[rr];
        }
        float psum = 0.f;
        #pragma unroll
        for (int i = 0; i < 16; ++i) { xv[i] = exp2f(xv[i] - mrun); psum += xv[i]; }
        lrun += psum;

        // ---- P -> aliased LDS slot (same-wave producer/consumer) ----
        #pragma unroll
        for (int st = 0; st < 4; ++st) {
            ushort4 w;
            w.x = f2bf(xv[st * 4 + 0]); w.y = f2bf(xv[st * 4 + 1]);
            w.z = f2bf(xv[st * 4 + 2]); w.w = f2bf(xv[st * 4 + 3]);
            const int slot8 = (st << 1) | (hi >> 1);
            *(ushort4*)&pb[qr * 64 + ((slot8 ^ (qr & 7)) << 3) + ((hi & 1) << 2)] = w;
        }

        // ---- O += P V ----
        #pragma unroll
        for (int ks = 0; ks < 2; ++ks) {
            if (!diag || wv >= 2 || ks == 0) {
                bf16x8 pa = *(const bf16x8*)&pb[qr * 64 + ((((ks << 2) | hi) ^ (qr & 7)) << 3)];
                #pragma unroll
                for (int dt = 0; dt < 4; ++dt) {
                    const int dv = dt * 16 + qr;
                    bf16x8 vbf = *(const bf16x8*)&lds_v[buf][dv * 64 + ((((ks << 2) + hi) ^ (dv & 7)) << 3)];
                    oacc[dt] = __builtin_amdgcn_mfma_f32_16x16x32_bf16(pa, vbf, oacc[dt], 0, 0, 0);
                }
            }
        }

        if (j + 1 < nit) stage_write(buf ^ 1);   // overwrites this iter's P (safe);
                                                 // compiler's vmcnt wait lands here
    }

    // ---- epilogue ----
    {
        float lr = lrun;
        lr += __shfl_xor(lr, 16);
        lr += __shfl_xor(lr, 32);
        const float linv = 1.0f / lr;
        #pragma unroll
        for (int rr = 0; rr < 4; ++rr) {
            const float inv = __shfl(linv, hi * 4 + rr);
            float* go = out + ((size_t)(b * TT + q0 + wv * 16 + hi * 4 + rr)) * DDIM + h * HD;
            #pragma unroll
            for (int dt = 0; dt < 4; ++dt)
                go[dt * 16 + qr] = oacc[dt][rr] * inv;
        }
    }
}

// ============ fallback (R6 kernel, proven 76.5us) if ws too small ============
#define VST 72
__global__ __launch_bounds__(256, 2)
void alibi_attn_fallback(const float* __restrict__ qg,
                         const float* __restrict__ kg,
                         const float* __restrict__ vg,
                         float* __restrict__ out) {
    __shared__ __align__(16) ushort lds_k[KVBLK * HD];
    __shared__ __align__(16) ushort lds_vt[HD * VST];
    __shared__ __align__(16) ushort lds_p[4][16 * 64];

    const int tid  = threadIdx.x;
    const int wv   = tid >> 6;
    const int lane = tid & 63;
    const int hi   = lane >> 4;
    const int qr   = lane & 15;

    const int flat = (int)blockIdx.x;
    const int xcd  = flat & 7;
    const int idx  = flat >> 3;
    const int bh   = xcd * 4 + (idx >> 5);
    const int qt   = NQT - 1 - (idx & 31);
    const int b    = bh >> 4;
    const int h    = bh & 15;
    const int q0   = qt * QBLK;

    const float LOG2E  = 1.4426950408889634f;
    const float slope2 = exp2f(-0.5f * (float)(h + 1)) * LOG2E;
    const float sc2    = 0.125f * LOG2E;

    const size_t bhbase = (size_t)(b * TT) * DDIM + (size_t)(h * HD);

    bf16x8 qf[2];
    {
        const float* gq = qg + bhbase + (size_t)(q0 + wv * 16 + qr) * DDIM + hi * 8;
        #pragma unroll
        for (int ch = 0; ch < 2; ++ch) {
            float4 a0 = *(const float4*)(gq + ch * 32);
            float4 a1 = *(const float4*)(gq + ch * 32 + 4);
            bf16x8 w;
            w[0]=f2bf(a0.x); w[1]=f2bf(a0.y); w[2]=f2bf(a0.z); w[3]=f2bf(a0.w);
            w[4]=f2bf(a1.x); w[5]=f2bf(a1.y); w[6]=f2bf(a1.z); w[7]=f2bf(a1.w);
            qf[ch] = w;
        }
    }

    const int krow = tid >> 3;
    const int kcg  = tid & 7;
    const int vdv  = tid & 63;
    const int vkc  = tid >> 6;

    float ka[2][8], va[2][8];
    auto issue_loads = [&](int kv0) {
        const float* kp0 = kg + bhbase + (size_t)(kv0 + krow) * DDIM + kcg * 8;
        const float* kp1 = kp0 + (size_t)32 * DDIM;
        *(float4*)&ka[0][0] = *(const float4*)kp0; *(float4*)&ka[0][4] = *(const float4*)(kp0 + 4);
        *(float4*)&ka[1][0] = *(const float4*)kp1; *(float4*)&ka[1][4] = *(const float4*)(kp1 + 4);
        const float* vp0 = vg + bhbase + (size_t)(kv0 + vkc * 8) * DDIM + vdv;
        const float* vp1 = vp0 + (size_t)32 * DDIM;
        #pragma unroll
        for (int jj = 0; jj < 8; ++jj) {
            va[0][jj] = vp0[(size_t)jj * DDIM];
            va[1][jj] = vp1[(size_t)jj * DDIM];
        }
    };
    auto write_stage = [&]() {
        #pragma unroll
        for (int s2 = 0; s2 < 2; ++s2) {
            bf16x8 w;
            #pragma unroll
            for (int e = 0; e < 8; ++e) w[e] = f2bf(ka[s2][e]);
            const int row = krow + s2 * 32;
            *(bf16x8*)&lds_k[row * 64 + ((kcg ^ (row & 7)) << 3)] = w;
            bf16x8 u;
            #pragma unroll
            for (int e = 0; e < 8; ++e) u[e] = f2bf(va[s2][e]);
            const int kc = vkc + s2 * 4;
            *(bf16x8*)&lds_vt[vdv * VST + ((kc ^ ((vdv >> 3) & 7)) << 3)] = u;
        }
    };

    const int nit = qt + 1;
    issue_loads(q0);
    write_stage();

    f32x4 oacc[4] = {};
    float mrun = -INFINITY, lrun = 0.f;

    for (int j = 0; j < nit; ++j) {
        const int kv0 = (qt - j) * KVBLK;
        if (j + 1 < nit) issue_loads(kv0 - KVBLK);
        __syncthreads();

        const bool diag = (j == 0);

        f32x4 s_acc[4] = {};
        #pragma unroll
        for (int st = 0; st < 4; ++st) {
            if (!diag || st <= wv) {
                const int kvrow = st * 16 + qr;
                #pragma unroll
                for (int ch = 0; ch < 2; ++ch) {
                    bf16x8 kf = *(const bf16x8*)&lds_k[kvrow * 64 + ((((ch << 2) + hi) ^ (kvrow & 7)) << 3)];
                    s_acc[st] = __builtin_amdgcn_mfma_f32_16x16x32_bf16(kf, qf[ch], s_acc[st], 0, 0, 0);
                }
            }
        }

        const int ti = q0 + wv * 16 + qr;
        float xv[16];
        float tm = -INFINITY;
        {
            const float relb = (float)(kv0 - ti);
            #pragma unroll
            for (int st = 0; st < 4; ++st)
                #pragma unroll
                for (int rr = 0; rr < 4; ++rr) {
                    const float rel = relb + (float)(st * 16 + hi * 4 + rr);
                    float v = s_acc[st][rr] * sc2 + rel * slope2;
                    if (diag) v = (rel <= 0.f) ? v : -INFINITY;
                    xv[st * 4 + rr] = v;
                    tm = fmaxf(tm, v);
                }
        }
        tm = fmaxf(tm, __shfl_xor(tm, 16));
        tm = fmaxf(tm, __shfl_xor(tm, 32));
        if (!__all(tm <= mrun + 8.f)) {
            const float mnew = fmaxf(mrun, tm);
            const float fsc  = exp2f(mrun - mnew);
            mrun = mnew;
            lrun *= fsc;
            float fo[4];
            #pragma unroll
            for (int rr = 0; rr < 4; ++rr) fo[rr] = __shfl(fsc, hi * 4 + rr);
            #pragma unroll
            for (int dt = 0; dt < 4; ++dt)
                #pragma unroll
                for (int rr = 0; rr < 4; ++rr) oacc[dt][rr] *= fo[rr];
        }
        float psum = 0.f;
        #pragma unroll
        for (int i = 0; i < 16; ++i) { xv[i] = exp2f(xv[i] - mrun); psum += xv[i]; }
        lrun += psum;

        #pragma unroll
        for (int st = 0; st < 4; ++st) {
            ushort4 w;
            w.x = f2bf(xv[st * 4 + 0]); w.y = f2bf(xv[st * 4 + 1]);
            w.z = f2bf(xv[st * 4 + 2]); w.w = f2bf(xv[st * 4 + 3]);
            const int slot8 = (st << 1) | (hi >> 1);
            *(ushort4*)&lds_p[wv][qr * 64 + ((slot8 ^ (qr & 7)) << 3) + ((hi & 1) << 2)] = w;
        }

        #pragma unroll
        for (int ks = 0; ks < 2; ++ks) {
            if (!diag || wv >= 2 || ks == 0) {
                bf16x8 pa = *(const bf16x8*)&lds_p[wv][qr * 64 + ((((ks << 2) | hi) ^ (qr & 7)) << 3)];
                #pragma unroll
                for (int dt = 0; dt < 4; ++dt) {
                    const int dv = dt * 16 + qr;
                    bf16x8 vbf = *(const bf16x8*)&lds_vt[dv * VST + ((((ks << 2) + hi) ^ ((dv >> 3) & 7)) << 3)];
                    oacc[dt] = __builtin_amdgcn_mfma_f32_16x16x32_bf16(pa, vbf, oacc[dt], 0, 0, 0);
                }
            }
        }

        if (j + 1 < nit) {
            __syncthreads();
            write_stage();
        }
    }

    {
        float lr = lrun;
        lr += __shfl_xor(lr, 16);
        lr += __shfl_xor(lr, 32);
        const float linv = 1.0f / lr;
        #pragma unroll
        for (int rr = 0; rr < 4; ++rr) {
            const float inv = __shfl(linv, hi * 4 + rr);
            float* go = out + bhbase + (size_t)(q0 + wv * 16 + hi * 4 + rr) * DDIM;
            #pragma unroll
            for (int dt = 0; dt < 4; ++dt)
                go[dt * 16 + qr] = oacc[dt][rr] * inv;
        }
    }
}

extern "C" void kernel_launch(void* const* d_in, const int* in_sizes, int n_in,
                              void* d_out, int out_size, void* d_ws, size_t ws_size,
                              hipStream_t stream) {
    (void)in_sizes; (void)n_in; (void)out_size;
    const float* q = (const float*)d_in[0];
    const float* k = (const float*)d_in[1];
    const float* v = (const float*)d_in[2];
    float* o = (float*)d_out;

    const size_t elems = (size_t)2 * NHEAD * TT * HD;
    const size_t kv_b  = 2 * elems * sizeof(ushort);       // 16.78 MB
    if (ws_size >= kv_b) {
        ushort* kbf = (ushort*)d_ws;
        ushort* vtt = kbf + elems;
        prepass_kernel<<<dim3(32, 32), 256, 0, stream>>>(k, v, kbf, vtt);
        attn_main<<<dim3(1024), 256, 0, stream>>>(q, kbf, vtt, o);
    } else {
        alibi_attn_fallback<<<dim3(1024), 256, 0, stream>>>(q, k, v, o);
    }
}